// Round 10
// baseline (640.252 us; speedup 1.0000x reference)
//
#include <hip/hip_runtime.h>
#include <hip/hip_bf16.h>

namespace {

constexpr int kV = 50000;
constexpr int kD = 128;
constexpr int kB = 512;
constexpr int kT = 256;
constexpr int kU = 256;

typedef __attribute__((ext_vector_type(8))) short  bfrag8;   // 8 x bf16 -> 4 VGPR (MFMA operand)
typedef __attribute__((ext_vector_type(4))) float  facc4;    // MFMA accumulator
typedef __attribute__((ext_vector_type(4))) float  vfloat4;
typedef __attribute__((ext_vector_type(2))) unsigned int vuint2;

__device__ __forceinline__ unsigned short f2bf(float f) {
  return __builtin_bit_cast(unsigned short, __float2bfloat16(f));
}
__device__ __forceinline__ float bf2f(unsigned short u) {
  unsigned int i = ((unsigned int)u) << 16;
  return __builtin_bit_cast(float, i);
}
__device__ __forceinline__ float bflo(unsigned v) {          // bf16 in low half
  return __builtin_bit_cast(float, v << 16);
}
__device__ __forceinline__ float bfhi(unsigned v) {          // bf16 in high half
  return __builtin_bit_cast(float, v & 0xffff0000u);
}
// 5-op tanh: 1 - 2*rcp(exp2(2x*log2e)+1). exp2 saturates -> no clamps needed.
__device__ __forceinline__ float tanh_fast(float x) {
  float e = __builtin_amdgcn_exp2f(x * 2.8853900817779268f);
  return fmaf(-2.f, __builtin_amdgcn_rcpf(e + 1.f), 1.f);
}
// LDS row swizzle (bits 4-6): byte-in-row = 2*col ^ swz(row). Conflict-free
// for b128 row-reads, b64 col-block writes, 8B/16B blocks never straddle.
__device__ __forceinline__ int swz(int row) {
  return ((row & 7) << 4) ^ ((row & 8) << 2);
}

// Non-draining workgroup barrier: orders LDS ops but leaves global loads in
// flight (they only write registers).
__device__ __forceinline__ void lds_barrier() {
  asm volatile("s_waitcnt lgkmcnt(0)\n\ts_barrier" ::: "memory");
}

// ---------------------------------------------------------------------------
// Pre-pass: EK[v][u] = bf16( emb[v][:] @ k0[:][u] + b0[u] )   (V x 256, bf16)
// ---------------------------------------------------------------------------
__global__ __launch_bounds__(256) void ek_prepass(
    const float* __restrict__ emb, const float* __restrict__ k0,
    const float* __restrict__ b0, __hip_bfloat16* __restrict__ EK)
{
  __shared__ __align__(16) unsigned short k0t[256 * 136];
  const int tid = threadIdx.x;

  for (int it = 0; it < 32; ++it) {
    int e = it * 1024 + tid * 4;
    int k = e >> 8, c = e & 255;
    vfloat4 wv = *(const vfloat4*)(k0 + e);
    #pragma unroll
    for (int i = 0; i < 4; ++i) k0t[(c + i) * 136 + k] = f2bf(wv[i]);
  }
  __syncthreads();

  const int l = tid & 63, w = tid >> 6;
  const int lr = l & 15, q = l >> 4;

  bfrag8 Fb[4][4];
  #pragma unroll
  for (int ut = 0; ut < 4; ++ut) {
    #pragma unroll
    for (int kt = 0; kt < 4; ++kt) {
      int col = w * 64 + ut * 16 + lr;
      Fb[ut][kt] = *(const bfrag8*)((const char*)k0t + col * 272 + kt * 64 + q * 16);
    }
  }

  float b0v[4];
  #pragma unroll
  for (int ut = 0; ut < 4; ++ut) b0v[ut] = b0[w * 64 + ut * 16 + lr];

  const int v0 = blockIdx.x * 128;
  for (int mt = 0; mt < 8; ++mt) {
    int vr = v0 + mt * 16 + lr;
    int vc = vr < kV ? vr : kV - 1;
    bfrag8 Fa[4];
    #pragma unroll
    for (int kt = 0; kt < 4; ++kt) {
      const vfloat4* p = (const vfloat4*)(emb + vc * kD + kt * 32 + q * 8);
      vfloat4 x0 = p[0], x1 = p[1];
      bfrag8 a;
      #pragma unroll
      for (int i = 0; i < 4; ++i) {
        a[i]     = (short)f2bf(x0[i]);
        a[i + 4] = (short)f2bf(x1[i]);
      }
      Fa[kt] = a;
    }
    facc4 acc[4];
    #pragma unroll
    for (int ut = 0; ut < 4; ++ut) {
      facc4 ini = {b0v[ut], b0v[ut], b0v[ut], b0v[ut]};
      acc[ut] = ini;
    }
    #pragma unroll
    for (int kt = 0; kt < 4; ++kt) {
      #pragma unroll
      for (int ut = 0; ut < 4; ++ut)
        acc[ut] = __builtin_amdgcn_mfma_f32_16x16x32_bf16(Fa[kt], Fb[ut][kt], acc[ut], 0, 0, 0);
    }
    #pragma unroll
    for (int ut = 0; ut < 4; ++ut) {
      #pragma unroll
      for (int r = 0; r < 4; ++r) {
        int row = v0 + mt * 16 + q * 4 + r;
        if (row < kV)
          EK[row * kU + w * 64 + ut * 16 + lr] = __float2bfloat16(acc[ut][r]);
      }
    }
  }
}

// ---------------------------------------------------------------------------
// Persistent RNN: 32 blocks x 512 threads (8 waves). Transposed MFMA
// (C^T = mfma(W_frag, h_frag)); merged-region schedule (G1(t) || G0(t+1),
// shared h0[t] reads); 6 independent 8-deep chains; setprio around MFMA;
// one non-draining barrier per region. NEW vs r7: 2x-unrolled main loop with
// COMPILE-TIME buffer bases (ds offsets fold to immediates, no cur/nxt
// selects) and idx register pipelining (gather consumes pre-loaded idxr).
// Buffers: h0[t] in h0s[(t+1)&1]; h1[t] in h1s[(t+1)&1].
// Region t: reads h0s[(t+1)&1], h1s[t&1]; writes h0s[t&1], h1s[(t+1)&1].
// ---------------------------------------------------------------------------
__global__ __launch_bounds__(512, 2) void rnn_persist(
    const int* __restrict__ inputs, const __hip_bfloat16* __restrict__ EK,
    const float* __restrict__ rk0g, const float* __restrict__ k1g,
    const float* __restrict__ rk1g, const float* __restrict__ b1,
    const float* __restrict__ wo, const float* __restrict__ bo,
    float* __restrict__ out)
{
  // h0s/h1s FIRST: keeps them in the 16-bit DS offset-immediate range.
  __shared__ __align__(16) unsigned short h0s[2][16 * 256];  // swizzled bf16
  __shared__ __align__(16) unsigned short h1s[2][16 * 256];
  __shared__ __align__(16) unsigned short wT[256 * 72];      // staging [col][k]
  __shared__ __align__(16) int idxs[16 * 257];               // [row][t], pitch 257

  const int tid = threadIdx.x, blk = blockIdx.x;
  const int l = tid & 63, w = tid >> 6;
  const int lr = l & 15, q = l >> 4;
  const int cbase = w * 32 + lr;               // weight-frag col base (+ut*16)
  const int sR = swz(lr);

  // ---- zero initial h state ----
  {
    bfrag8 z = {0, 0, 0, 0, 0, 0, 0, 0};
    *(bfrag8*)((char*)h0s[0] + tid * 16) = z;
    *(bfrag8*)((char*)h1s[0] + tid * 16) = z;
  }

  // ---- stage weights into per-wave register fragments (ALL loops unrolled) --
  bfrag8 Frk0[2][8], Fk1[2][8], Frk1[2][8];

#define STAGE_MAT(SRC, DST)                                                    \
  _Pragma("unroll")                                                            \
  for (int c = 0; c < 4; ++c) {                                                \
    __syncthreads();                                                           \
    for (int it = 0; it < 8; ++it) {                                           \
      int e = it * 2048 + tid * 4;                                             \
      int k = e >> 8, col = e & 255;                                           \
      vfloat4 wv = *(const vfloat4*)(SRC + (c * 64 + k) * 256 + col);          \
      _Pragma("unroll")                                                        \
      for (int i2 = 0; i2 < 4; ++i2) wT[(col + i2) * 72 + k] = f2bf(wv[i2]);   \
    }                                                                          \
    __syncthreads();                                                           \
    _Pragma("unroll")                                                          \
    for (int ut = 0; ut < 2; ++ut) {                                           \
      _Pragma("unroll")                                                        \
      for (int kk = 0; kk < 2; ++kk)                                           \
        DST[ut][c * 2 + kk] = *(const bfrag8*)((const char*)wT +               \
            (cbase + ut * 16) * 144 + kk * 64 + q * 16);                       \
    }                                                                          \
  }

  STAGE_MAT(rk0g, Frk0);
  STAGE_MAT(k1g, Fk1);
  STAGE_MAT(rk1g, Frk1);
#undef STAGE_MAT

  // ---- stage this block's indices: idxs[row][t] ----
  for (int it = 0; it < 8; ++it) {
    int e = it * 512 + tid;                    // e = row*256 + t
    int row = e >> 8, tt = e & 255;
    idxs[row * 257 + tt] = inputs[(blk * 16 + row) * kT + tt];
  }

  // ---- per-lane constants (transposed C layout) ----
  float b1vv[2][4];                            // b1[outcol], outcol = w*32+ut*16+q*4+r
  #pragma unroll
  for (int ut = 0; ut < 2; ++ut) {
    vfloat4 bv = *(const vfloat4*)(b1 + w * 32 + ut * 16 + q * 4);
    #pragma unroll
    for (int r = 0; r < 4; ++r) b1vv[ut][r] = bv[r];
  }
  int roff[8];                                 // h-state b128 read offsets
  #pragma unroll
  for (int kt = 0; kt < 8; ++kt) roff[kt] = lr * 512 + ((kt * 64 + q * 16) ^ sR);
  int wb[2];                                   // b64 write offsets (row lr, 4 cols)
  #pragma unroll
  for (int ut = 0; ut < 2; ++ut)
    wb[ut] = lr * 512 + ((64 * w + 32 * ut + 8 * q) ^ sR);
  // EK gather base: lane loads 8B = 4 cols (q*4..q*4+3) of its own row's EK
  const char* ekg = (const char*)EK + 64 * w + 8 * q;
  const int idxrow = lr * 257;

  __syncthreads();                             // idxs + h-zero visible

  // ---- prologue: h0[0] = tanh(EK[x_0]); gather EK[x_1]; preload idx[2] ----
  vuint2 ekq0, ekq1;
  int idxr;
  {
    int i0 = idxs[idxrow + 0];
    const char* gp = ekg + (size_t)(unsigned)i0 * 512;
    vuint2 e0 = *(const vuint2*)(gp);
    vuint2 e1 = *(const vuint2*)(gp + 32);
    float v0[4] = {bflo(e0[0]), bfhi(e0[0]), bflo(e0[1]), bfhi(e0[1])};
    float v1[4] = {bflo(e1[0]), bfhi(e1[0]), bflo(e1[1]), bfhi(e1[1])};
    unsigned lo0 = f2bf(tanh_fast(v0[0])) | ((unsigned)f2bf(tanh_fast(v0[1])) << 16);
    unsigned hi0 = f2bf(tanh_fast(v0[2])) | ((unsigned)f2bf(tanh_fast(v0[3])) << 16);
    unsigned lo1 = f2bf(tanh_fast(v1[0])) | ((unsigned)f2bf(tanh_fast(v1[1])) << 16);
    unsigned hi1 = f2bf(tanh_fast(v1[2])) | ((unsigned)f2bf(tanh_fast(v1[3])) << 16);
    vuint2 p0 = {lo0, hi0}, p1 = {lo1, hi1};
    *(vuint2*)((char*)h0s[1] + wb[0]) = p0;
    *(vuint2*)((char*)h0s[1] + wb[1]) = p1;
    int i1 = idxs[idxrow + 1];
    const char* gp1 = ekg + (size_t)(unsigned)i1 * 512;
    ekq0 = *(const vuint2*)(gp1);
    ekq1 = *(const vuint2*)(gp1 + 32);
    idxr = idxs[idxrow + 2];
  }
  lds_barrier();

  // ---- merged-region body. H0C/H0N/H1P/H1N are ARRAY EXPRESSIONS so the
  //      ds_read/ds_write addresses fold to base-immediates (no v_adds). ----
#define REGION(T, H0C, H0N, H1P, H1N)                                          \
  {                                                                            \
    facc4 a1A[2], a1B[2], a0c[2];                                              \
    _Pragma("unroll")                                                          \
    for (int ut = 0; ut < 2; ++ut) {                                           \
      facc4 ini = {b1vv[ut][0], b1vv[ut][1], b1vv[ut][2], b1vv[ut][3]};        \
      a1A[ut] = ini;                                                           \
      facc4 zz = {0.f, 0.f, 0.f, 0.f};                                         \
      a1B[ut] = zz;                                                            \
    }                                                                          \
    a0c[0][0] = bflo(ekq0[0]); a0c[0][1] = bfhi(ekq0[0]);                      \
    a0c[0][2] = bflo(ekq0[1]); a0c[0][3] = bfhi(ekq0[1]);                      \
    a0c[1][0] = bflo(ekq1[0]); a0c[1][1] = bfhi(ekq1[0]);                      \
    a0c[1][2] = bflo(ekq1[1]); a0c[1][3] = bfhi(ekq1[1]);                      \
    {  /* issue EK gather for x_{T+2} using pre-loaded idxr */                 \
      const char* gp = ekg + (size_t)(unsigned)idxr * 512;                     \
      ekq0 = *(const vuint2*)(gp);                                             \
      ekq1 = *(const vuint2*)(gp + 32);                                        \
      int tn = (T) + 3; tn = tn < kT ? tn : kT - 1;                            \
      idxr = idxs[idxrow + tn];                                                \
    }                                                                          \
    __builtin_amdgcn_s_setprio(1);                                             \
    _Pragma("unroll")                                                          \
    for (int kt = 0; kt < 8; ++kt) {                                           \
      bfrag8 vh0 = *(const bfrag8*)((const char*)(H0C) + roff[kt]);            \
      bfrag8 vh1 = *(const bfrag8*)((const char*)(H1P) + roff[kt]);            \
      a1A[0] = __builtin_amdgcn_mfma_f32_16x16x32_bf16(Fk1[0][kt],  vh0, a1A[0], 0, 0, 0); \
      a1A[1] = __builtin_amdgcn_mfma_f32_16x16x32_bf16(Fk1[1][kt],  vh0, a1A[1], 0, 0, 0); \
      a0c[0] = __builtin_amdgcn_mfma_f32_16x16x32_bf16(Frk0[0][kt], vh0, a0c[0], 0, 0, 0); \
      a0c[1] = __builtin_amdgcn_mfma_f32_16x16x32_bf16(Frk0[1][kt], vh0, a0c[1], 0, 0, 0); \
      a1B[0] = __builtin_amdgcn_mfma_f32_16x16x32_bf16(Frk1[0][kt], vh1, a1B[0], 0, 0, 0); \
      a1B[1] = __builtin_amdgcn_mfma_f32_16x16x32_bf16(Frk1[1][kt], vh1, a1B[1], 0, 0, 0); \
    }                                                                          \
    __builtin_amdgcn_s_setprio(0);                                             \
    _Pragma("unroll")                                                          \
    for (int ut = 0; ut < 2; ++ut) {                                           \
      float s0 = tanh_fast(a1A[ut][0] + a1B[ut][0]);                           \
      float s1 = tanh_fast(a1A[ut][1] + a1B[ut][1]);                           \
      float s2 = tanh_fast(a1A[ut][2] + a1B[ut][2]);                           \
      float s3 = tanh_fast(a1A[ut][3] + a1B[ut][3]);                           \
      unsigned lo = f2bf(s0) | ((unsigned)f2bf(s1) << 16);                     \
      unsigned hi = f2bf(s2) | ((unsigned)f2bf(s3) << 16);                     \
      vuint2 pk = {lo, hi};                                                    \
      *(vuint2*)((char*)(H1N) + wb[ut]) = pk;                                  \
      float u0 = tanh_fast(a0c[ut][0]);                                        \
      float u1 = tanh_fast(a0c[ut][1]);                                        \
      float u2 = tanh_fast(a0c[ut][2]);                                        \
      float u3 = tanh_fast(a0c[ut][3]);                                        \
      unsigned lo2 = f2bf(u0) | ((unsigned)f2bf(u1) << 16);                    \
      unsigned hi2 = f2bf(u2) | ((unsigned)f2bf(u3) << 16);                    \
      vuint2 pk2 = {lo2, hi2};                                                 \
      *(vuint2*)((char*)(H0N) + wb[ut]) = pk2;                                 \
    }                                                                          \
    lds_barrier();                                                             \
  }

  // regions 0..253 as 127 even/odd pairs, region 254 single (parity checked)
  for (int tt = 0; tt < 127; ++tt) {
    const int t0 = 2 * tt;
    REGION(t0,     h0s[1], h0s[0], h1s[0], h1s[1]);   // t even
    REGION(t0 + 1, h0s[0], h0s[1], h1s[1], h1s[0]);   // t odd
  }
  REGION(254, h0s[1], h0s[0], h1s[0], h1s[1]);        // t = 254 (even)
#undef REGION

  // ---- peeled final region: G1(255) only; h0[255] in h0s[0], h1[254] in
  //      h1s[1]; h1[255] -> h1s[0] (epilogue reads h1s[0]) ----
  {
    facc4 a1A[2], a1B[2];
    #pragma unroll
    for (int ut = 0; ut < 2; ++ut) {
      facc4 ini = {b1vv[ut][0], b1vv[ut][1], b1vv[ut][2], b1vv[ut][3]};
      a1A[ut] = ini;
      facc4 zz = {0.f, 0.f, 0.f, 0.f};
      a1B[ut] = zz;
    }
    #pragma unroll
    for (int kt = 0; kt < 8; ++kt) {
      bfrag8 vh0 = *(const bfrag8*)((const char*)h0s[0] + roff[kt]);
      bfrag8 vh1 = *(const bfrag8*)((const char*)h1s[1] + roff[kt]);
      #pragma unroll
      for (int ut = 0; ut < 2; ++ut) {
        a1A[ut] = __builtin_amdgcn_mfma_f32_16x16x32_bf16(Fk1[ut][kt],  vh0, a1A[ut], 0, 0, 0);
        a1B[ut] = __builtin_amdgcn_mfma_f32_16x16x32_bf16(Frk1[ut][kt], vh1, a1B[ut], 0, 0, 0);
      }
    }
    #pragma unroll
    for (int ut = 0; ut < 2; ++ut) {
      float s0 = tanh_fast(a1A[ut][0] + a1B[ut][0]);
      float s1 = tanh_fast(a1A[ut][1] + a1B[ut][1]);
      float s2 = tanh_fast(a1A[ut][2] + a1B[ut][2]);
      float s3 = tanh_fast(a1A[ut][3] + a1B[ut][3]);
      unsigned lo = f2bf(s0) | ((unsigned)f2bf(s1) << 16);
      unsigned hi = f2bf(s2) | ((unsigned)f2bf(s3) << 16);
      vuint2 pk = {lo, hi};
      *(vuint2*)((char*)h1s[0] + wb[ut]) = pk;
    }
  }
  __syncthreads();

  // ---- epilogue: out = sigmoid(h1[T-1] @ wo + bo); h1[T-1] is in h1s[0] ----
  if (w == 0) {
    float dot = 0.f;
    #pragma unroll
    for (int c8 = 0; c8 < 8; ++c8) {
      int colb = (q * 64 + c8 * 8) * 2;
      bfrag8 hv = *(const bfrag8*)((const char*)h1s[0] + lr * 512 + (colb ^ sR));
      #pragma unroll
      for (int j = 0; j < 8; ++j)
        dot += bf2f((unsigned short)hv[j]) * wo[q * 64 + c8 * 8 + j];
    }
    dot += __shfl_xor(dot, 16);
    dot += __shfl_xor(dot, 32);
    if (l < 16) {
      float z = dot + bo[0];
      z = fminf(30.f, fmaxf(-30.f, z));
      out[blk * 16 + lr] = __fdividef(1.f, 1.f + __expf(-z));
    }
  }
}

}  // namespace

extern "C" void kernel_launch(void* const* d_in, const int* in_sizes, int n_in,
                              void* d_out, int out_size, void* d_ws, size_t ws_size,
                              hipStream_t stream) {
  const int*   inputs = (const int*)  d_in[0];
  const float* emb    = (const float*)d_in[1];
  const float* k0     = (const float*)d_in[2];
  const float* rk0    = (const float*)d_in[3];
  const float* b0     = (const float*)d_in[4];
  const float* k1     = (const float*)d_in[5];
  const float* rk1    = (const float*)d_in[6];
  const float* b1     = (const float*)d_in[7];
  const float* wo     = (const float*)d_in[8];
  const float* bo     = (const float*)d_in[9];
  float* out = (float*)d_out;

  __hip_bfloat16* EK = (__hip_bfloat16*)d_ws;          // V*U bf16 = 25.6 MB
  if (ws_size < (size_t)kV * kU * sizeof(__hip_bfloat16)) return;

  ek_prepass<<<(kV + 127) / 128, 256, 0, stream>>>(emb, k0, b0, EK);
  rnn_persist<<<kB / 16, 512, 0, stream>>>(inputs, EK, rk0, k1, rk1, b1, wo, bo, out);
}

// Round 11
// 443.949 us; speedup vs baseline: 1.4422x; 1.4422x over previous
//
#include <hip/hip_runtime.h>
#include <hip/hip_bf16.h>

namespace {

constexpr int kV = 50000;
constexpr int kD = 128;
constexpr int kB = 512;
constexpr int kT = 256;
constexpr int kU = 256;

typedef __attribute__((ext_vector_type(8))) short  bfrag8;   // 8 x bf16 -> 4 VGPR (MFMA operand)
typedef __attribute__((ext_vector_type(4))) float  facc4;    // MFMA accumulator
typedef __attribute__((ext_vector_type(4))) float  vfloat4;
typedef __attribute__((ext_vector_type(2))) unsigned int vuint2;

__device__ __forceinline__ unsigned short f2bf(float f) {
  return __builtin_bit_cast(unsigned short, __float2bfloat16(f));
}
__device__ __forceinline__ float bf2f(unsigned short u) {
  unsigned int i = ((unsigned int)u) << 16;
  return __builtin_bit_cast(float, i);
}
__device__ __forceinline__ float bflo(unsigned v) {          // bf16 in low half
  return __builtin_bit_cast(float, v << 16);
}
__device__ __forceinline__ float bfhi(unsigned v) {          // bf16 in high half
  return __builtin_bit_cast(float, v & 0xffff0000u);
}
// 5-op tanh: 1 - 2*rcp(exp2(2x*log2e)+1). exp2 saturates -> no clamps needed.
__device__ __forceinline__ float tanh_fast(float x) {
  float e = __builtin_amdgcn_exp2f(x * 2.8853900817779268f);
  return fmaf(-2.f, __builtin_amdgcn_rcpf(e + 1.f), 1.f);
}
// LDS row swizzle (bits 4-6): byte-in-row = 2*col ^ swz(row). Conflict-free
// for b128 row-reads, b64 col-block writes, 8B/16B blocks never straddle.
__device__ __forceinline__ int swz(int row) {
  return ((row & 7) << 4) ^ ((row & 8) << 2);
}

// Non-draining workgroup barrier: orders LDS ops but leaves global loads in
// flight (they only write registers).
__device__ __forceinline__ void lds_barrier() {
  asm volatile("s_waitcnt lgkmcnt(0)\n\ts_barrier" ::: "memory");
}

// ---------------------------------------------------------------------------
// Pre-pass: EK[v][u] = bf16( emb[v][:] @ k0[:][u] + b0[u] )   (V x 256, bf16)
// ---------------------------------------------------------------------------
__global__ __launch_bounds__(256) void ek_prepass(
    const float* __restrict__ emb, const float* __restrict__ k0,
    const float* __restrict__ b0, __hip_bfloat16* __restrict__ EK)
{
  __shared__ __align__(16) unsigned short k0t[256 * 136];
  const int tid = threadIdx.x;

  for (int it = 0; it < 32; ++it) {
    int e = it * 1024 + tid * 4;
    int k = e >> 8, c = e & 255;
    vfloat4 wv = *(const vfloat4*)(k0 + e);
    #pragma unroll
    for (int i = 0; i < 4; ++i) k0t[(c + i) * 136 + k] = f2bf(wv[i]);
  }
  __syncthreads();

  const int l = tid & 63, w = tid >> 6;
  const int lr = l & 15, q = l >> 4;

  bfrag8 Fb[4][4];
  #pragma unroll
  for (int ut = 0; ut < 4; ++ut) {
    #pragma unroll
    for (int kt = 0; kt < 4; ++kt) {
      int col = w * 64 + ut * 16 + lr;
      Fb[ut][kt] = *(const bfrag8*)((const char*)k0t + col * 272 + kt * 64 + q * 16);
    }
  }

  float b0v[4];
  #pragma unroll
  for (int ut = 0; ut < 4; ++ut) b0v[ut] = b0[w * 64 + ut * 16 + lr];

  const int v0 = blockIdx.x * 128;
  for (int mt = 0; mt < 8; ++mt) {
    int vr = v0 + mt * 16 + lr;
    int vc = vr < kV ? vr : kV - 1;
    bfrag8 Fa[4];
    #pragma unroll
    for (int kt = 0; kt < 4; ++kt) {
      const vfloat4* p = (const vfloat4*)(emb + vc * kD + kt * 32 + q * 8);
      vfloat4 x0 = p[0], x1 = p[1];
      bfrag8 a;
      #pragma unroll
      for (int i = 0; i < 4; ++i) {
        a[i]     = (short)f2bf(x0[i]);
        a[i + 4] = (short)f2bf(x1[i]);
      }
      Fa[kt] = a;
    }
    facc4 acc[4];
    #pragma unroll
    for (int ut = 0; ut < 4; ++ut) {
      facc4 ini = {b0v[ut], b0v[ut], b0v[ut], b0v[ut]};
      acc[ut] = ini;
    }
    #pragma unroll
    for (int kt = 0; kt < 4; ++kt) {
      #pragma unroll
      for (int ut = 0; ut < 4; ++ut)
        acc[ut] = __builtin_amdgcn_mfma_f32_16x16x32_bf16(Fa[kt], Fb[ut][kt], acc[ut], 0, 0, 0);
    }
    #pragma unroll
    for (int ut = 0; ut < 4; ++ut) {
      #pragma unroll
      for (int r = 0; r < 4; ++r) {
        int row = v0 + mt * 16 + q * 4 + r;
        if (row < kV)
          EK[row * kU + w * 64 + ut * 16 + lr] = __float2bfloat16(acc[ut][r]);
      }
    }
  }
}

// ---------------------------------------------------------------------------
// Persistent RNN: 32 blocks x 512 threads (8 waves). TRANSPOSED MFMA:
// C^T = mfma(W_frag, h_frag) -- A/B fragment layouts are symmetric, so the
// weight fragments and h-state LDS reads are identical to the non-transposed
// form; only C changes: lane owns batch-row lr and 4 CONTIGUOUS output cols
// (q*4+r). Writes become 2xds_write_b64/state, EK gathers 2x8B coalesced,
// idx one LDS read. Merged-region schedule (G1(t) || G0(t+1), shared h0[t]
// reads), 6 independent 8-deep MFMA chains, setprio(1) around the cluster,
// one non-draining barrier per region.
// Buffers: h0[t] in h0s[(t+1)&1]; h1[t] in h1s[(t+1)&1].
// Region t: reads h0s[(t+1)&1], h1s[t&1]; writes h0s[t&1], h1s[(t+1)&1].
// ---------------------------------------------------------------------------
__global__ __launch_bounds__(512, 2) void rnn_persist(
    const int* __restrict__ inputs, const __hip_bfloat16* __restrict__ EK,
    const float* __restrict__ rk0g, const float* __restrict__ k1g,
    const float* __restrict__ rk1g, const float* __restrict__ b1,
    const float* __restrict__ wo, const float* __restrict__ bo,
    float* __restrict__ out)
{
  __shared__ __align__(16) unsigned short h0s[2][16 * 256];  // swizzled bf16
  __shared__ __align__(16) unsigned short h1s[2][16 * 256];
  __shared__ __align__(16) unsigned short wT[256 * 72];      // staging [col][k]
  __shared__ __align__(16) int idxs[16 * 257];               // [row][t], pitch 257

  const int tid = threadIdx.x, blk = blockIdx.x;
  const int l = tid & 63, w = tid >> 6;
  const int lr = l & 15, q = l >> 4;
  const int cbase = w * 32 + lr;               // weight-frag col base (+ut*16)
  const int sR = swz(lr);

  // ---- zero initial h state (h1s[0] read as h1[-1]; h0s zero for safety) ----
  {
    bfrag8 z = {0, 0, 0, 0, 0, 0, 0, 0};
    *(bfrag8*)((char*)h0s[0] + tid * 16) = z;
    *(bfrag8*)((char*)h1s[0] + tid * 16) = z;
  }

  // ---- stage weights into per-wave register fragments (ALL loops unrolled) --
  bfrag8 Frk0[2][8], Fk1[2][8], Frk1[2][8];

#define STAGE_MAT(SRC, DST)                                                    \
  _Pragma("unroll")                                                            \
  for (int c = 0; c < 4; ++c) {                                                \
    __syncthreads();                                                           \
    for (int it = 0; it < 8; ++it) {                                           \
      int e = it * 2048 + tid * 4;                                             \
      int k = e >> 8, col = e & 255;                                           \
      vfloat4 wv = *(const vfloat4*)(SRC + (c * 64 + k) * 256 + col);          \
      _Pragma("unroll")                                                        \
      for (int i2 = 0; i2 < 4; ++i2) wT[(col + i2) * 72 + k] = f2bf(wv[i2]);   \
    }                                                                          \
    __syncthreads();                                                           \
    _Pragma("unroll")                                                          \
    for (int ut = 0; ut < 2; ++ut) {                                           \
      _Pragma("unroll")                                                        \
      for (int kk = 0; kk < 2; ++kk)                                           \
        DST[ut][c * 2 + kk] = *(const bfrag8*)((const char*)wT +               \
            (cbase + ut * 16) * 144 + kk * 64 + q * 16);                       \
    }                                                                          \
  }

  STAGE_MAT(rk0g, Frk0);
  STAGE_MAT(k1g, Fk1);
  STAGE_MAT(rk1g, Frk1);
#undef STAGE_MAT

  // ---- stage this block's indices: idxs[row][t] ----
  for (int it = 0; it < 8; ++it) {
    int e = it * 512 + tid;                    // e = row*256 + t
    int row = e >> 8, tt = e & 255;
    idxs[row * 257 + tt] = inputs[(blk * 16 + row) * kT + tt];
  }

  // ---- per-lane constants (transposed C layout) ----
  float b1vv[2][4];                            // b1[outcol], outcol = w*32+ut*16+q*4+r
  #pragma unroll
  for (int ut = 0; ut < 2; ++ut) {
    vfloat4 bv = *(const vfloat4*)(b1 + w * 32 + ut * 16 + q * 4);
    #pragma unroll
    for (int r = 0; r < 4; ++r) b1vv[ut][r] = bv[r];
  }
  int roff[8];                                 // h-state b128 read offsets
  #pragma unroll
  for (int kt = 0; kt < 8; ++kt) roff[kt] = lr * 512 + ((kt * 64 + q * 16) ^ sR);
  int wb[2];                                   // b64 write offsets (row lr, 4 cols)
  #pragma unroll
  for (int ut = 0; ut < 2; ++ut)
    wb[ut] = lr * 512 + ((64 * w + 32 * ut + 8 * q) ^ sR);
  // EK gather base: lane loads 8B = 4 cols (q*4..q*4+3) of its own row's EK
  const char* ekg = (const char*)EK + 64 * w + 8 * q;

  __syncthreads();                             // idxs + h-zero visible

  // ---- prologue: h0[0] = tanh(EK[x_0]); then gather EK[x_1] ----
  vuint2 ekq0, ekq1;
  {
    int i0 = idxs[lr * 257 + 0];
    const char* gp = ekg + (size_t)(unsigned)i0 * 512;
    vuint2 e0 = *(const vuint2*)(gp);
    vuint2 e1 = *(const vuint2*)(gp + 32);
    float v0[4] = {bflo(e0[0]), bfhi(e0[0]), bflo(e0[1]), bfhi(e0[1])};
    float v1[4] = {bflo(e1[0]), bfhi(e1[0]), bflo(e1[1]), bfhi(e1[1])};
    unsigned lo0 = f2bf(tanh_fast(v0[0])) | ((unsigned)f2bf(tanh_fast(v0[1])) << 16);
    unsigned hi0 = f2bf(tanh_fast(v0[2])) | ((unsigned)f2bf(tanh_fast(v0[3])) << 16);
    unsigned lo1 = f2bf(tanh_fast(v1[0])) | ((unsigned)f2bf(tanh_fast(v1[1])) << 16);
    unsigned hi1 = f2bf(tanh_fast(v1[2])) | ((unsigned)f2bf(tanh_fast(v1[3])) << 16);
    vuint2 p0 = {lo0, hi0}, p1 = {lo1, hi1};
    *(vuint2*)((char*)h0s[1] + wb[0]) = p0;
    *(vuint2*)((char*)h0s[1] + wb[1]) = p1;
    int i1 = idxs[lr * 257 + 1];
    const char* gp1 = ekg + (size_t)(unsigned)i1 * 512;
    ekq0 = *(const vuint2*)(gp1);
    ekq1 = *(const vuint2*)(gp1 + 32);
  }
  lds_barrier();

  // ---- merged-region main loop: region t = G1(t) || G0(t+1), one barrier ----
  for (int t = 0; t < kT - 1; ++t) {
    const char* h0cur = (const char*)h0s[(t + 1) & 1];  // h0[t]   (read, shared)
    char*       h0nxt = (char*)h0s[t & 1];              // h0[t+1] (write)
    const char* h1prv = (const char*)h1s[t & 1];        // h1[t-1] (read)
    char*       h1nxt = (char*)h1s[(t + 1) & 1];        // h1[t]   (write)

    facc4 a1A[2], a1B[2], a0c[2];              // 6 independent 8-deep chains
    #pragma unroll
    for (int ut = 0; ut < 2; ++ut) {
      facc4 ini = {b1vv[ut][0], b1vv[ut][1], b1vv[ut][2], b1vv[ut][3]};
      a1A[ut] = ini;
      facc4 zz = {0.f, 0.f, 0.f, 0.f};
      a1B[ut] = zz;
    }
    a0c[0][0] = bflo(ekq0[0]); a0c[0][1] = bfhi(ekq0[0]);  // EK[x_{t+1}]
    a0c[0][2] = bflo(ekq0[1]); a0c[0][3] = bfhi(ekq0[1]);
    a0c[1][0] = bflo(ekq1[0]); a0c[1][1] = bfhi(ekq1[0]);
    a0c[1][2] = bflo(ekq1[1]); a0c[1][3] = bfhi(ekq1[1]);

    // issue EK gather for x_{t+2} (in flight across the barrier)
    {
      int tn = (t + 2 < kT) ? t + 2 : kT - 1;
      int nidx = idxs[lr * 257 + tn];
      const char* gp = ekg + (size_t)(unsigned)nidx * 512;
      ekq0 = *(const vuint2*)(gp);
      ekq1 = *(const vuint2*)(gp + 32);
    }

    // interleaved MFMA (transposed: A = weights, B = h-state)
    __builtin_amdgcn_s_setprio(1);
    #pragma unroll
    for (int kt = 0; kt < 8; ++kt) {
      bfrag8 vh0 = *(const bfrag8*)(h0cur + roff[kt]);
      bfrag8 vh1 = *(const bfrag8*)(h1prv + roff[kt]);
      a1A[0] = __builtin_amdgcn_mfma_f32_16x16x32_bf16(Fk1[0][kt],  vh0, a1A[0], 0, 0, 0);
      a1A[1] = __builtin_amdgcn_mfma_f32_16x16x32_bf16(Fk1[1][kt],  vh0, a1A[1], 0, 0, 0);
      a0c[0] = __builtin_amdgcn_mfma_f32_16x16x32_bf16(Frk0[0][kt], vh0, a0c[0], 0, 0, 0);
      a0c[1] = __builtin_amdgcn_mfma_f32_16x16x32_bf16(Frk0[1][kt], vh0, a0c[1], 0, 0, 0);
      a1B[0] = __builtin_amdgcn_mfma_f32_16x16x32_bf16(Frk1[0][kt], vh1, a1B[0], 0, 0, 0);
      a1B[1] = __builtin_amdgcn_mfma_f32_16x16x32_bf16(Frk1[1][kt], vh1, a1B[1], 0, 0, 0);
    }
    __builtin_amdgcn_s_setprio(0);

    // writes: h1[t] and h0[t+1] -- 4 contiguous cols per lane, b64 each
    #pragma unroll
    for (int ut = 0; ut < 2; ++ut) {
      float s0 = tanh_fast(a1A[ut][0] + a1B[ut][0]);
      float s1 = tanh_fast(a1A[ut][1] + a1B[ut][1]);
      float s2 = tanh_fast(a1A[ut][2] + a1B[ut][2]);
      float s3 = tanh_fast(a1A[ut][3] + a1B[ut][3]);
      unsigned lo = f2bf(s0) | ((unsigned)f2bf(s1) << 16);
      unsigned hi = f2bf(s2) | ((unsigned)f2bf(s3) << 16);
      vuint2 pk = {lo, hi};
      *(vuint2*)(h1nxt + wb[ut]) = pk;
      float u0 = tanh_fast(a0c[ut][0]);
      float u1 = tanh_fast(a0c[ut][1]);
      float u2 = tanh_fast(a0c[ut][2]);
      float u3 = tanh_fast(a0c[ut][3]);
      unsigned lo2 = f2bf(u0) | ((unsigned)f2bf(u1) << 16);
      unsigned hi2 = f2bf(u2) | ((unsigned)f2bf(u3) << 16);
      vuint2 pk2 = {lo2, hi2};
      *(vuint2*)(h0nxt + wb[ut]) = pk2;
    }
    lds_barrier();
  }

  // ---- peeled final region: G1(kT-1) only ----
  {
    const int t = kT - 1;
    const char* h0cur = (const char*)h0s[(t + 1) & 1];
    const char* h1prv = (const char*)h1s[t & 1];
    char*       h1nxt = (char*)h1s[(t + 1) & 1];
    facc4 a1A[2], a1B[2];
    #pragma unroll
    for (int ut = 0; ut < 2; ++ut) {
      facc4 ini = {b1vv[ut][0], b1vv[ut][1], b1vv[ut][2], b1vv[ut][3]};
      a1A[ut] = ini;
      facc4 zz = {0.f, 0.f, 0.f, 0.f};
      a1B[ut] = zz;
    }
    #pragma unroll
    for (int kt = 0; kt < 8; ++kt) {
      bfrag8 vh0 = *(const bfrag8*)(h0cur + roff[kt]);
      bfrag8 vh1 = *(const bfrag8*)(h1prv + roff[kt]);
      #pragma unroll
      for (int ut = 0; ut < 2; ++ut) {
        a1A[ut] = __builtin_amdgcn_mfma_f32_16x16x32_bf16(Fk1[ut][kt],  vh0, a1A[ut], 0, 0, 0);
        a1B[ut] = __builtin_amdgcn_mfma_f32_16x16x32_bf16(Frk1[ut][kt], vh1, a1B[ut], 0, 0, 0);
      }
    }
    #pragma unroll
    for (int ut = 0; ut < 2; ++ut) {
      float s0 = tanh_fast(a1A[ut][0] + a1B[ut][0]);
      float s1 = tanh_fast(a1A[ut][1] + a1B[ut][1]);
      float s2 = tanh_fast(a1A[ut][2] + a1B[ut][2]);
      float s3 = tanh_fast(a1A[ut][3] + a1B[ut][3]);
      unsigned lo = f2bf(s0) | ((unsigned)f2bf(s1) << 16);
      unsigned hi = f2bf(s2) | ((unsigned)f2bf(s3) << 16);
      vuint2 pk = {lo, hi};
      *(vuint2*)(h1nxt + wb[ut]) = pk;
    }
  }
  __syncthreads();

  // ---- epilogue: out = sigmoid(h1[T-1] @ wo + bo); h1[T-1] is in h1s[0] ----
  if (w == 0) {
    float dot = 0.f;
    #pragma unroll
    for (int c8 = 0; c8 < 8; ++c8) {
      int colb = (q * 64 + c8 * 8) * 2;
      bfrag8 hv = *(const bfrag8*)((const char*)h1s[0] + lr * 512 + (colb ^ sR));
      #pragma unroll
      for (int j = 0; j < 8; ++j)
        dot += bf2f((unsigned short)hv[j]) * wo[q * 64 + c8 * 8 + j];
    }
    dot += __shfl_xor(dot, 16);
    dot += __shfl_xor(dot, 32);
    if (l < 16) {
      float z = dot + bo[0];
      z = fminf(30.f, fmaxf(-30.f, z));
      out[blk * 16 + lr] = __fdividef(1.f, 1.f + __expf(-z));
    }
  }
}

}  // namespace

extern "C" void kernel_launch(void* const* d_in, const int* in_sizes, int n_in,
                              void* d_out, int out_size, void* d_ws, size_t ws_size,
                              hipStream_t stream) {
  const int*   inputs = (const int*)  d_in[0];
  const float* emb    = (const float*)d_in[1];
  const float* k0     = (const float*)d_in[2];
  const float* rk0    = (const float*)d_in[3];
  const float* b0     = (const float*)d_in[4];
  const float* k1     = (const float*)d_in[5];
  const float* rk1    = (const float*)d_in[6];
  const float* b1     = (const float*)d_in[7];
  const float* wo     = (const float*)d_in[8];
  const float* bo     = (const float*)d_in[9];
  float* out = (float*)d_out;

  __hip_bfloat16* EK = (__hip_bfloat16*)d_ws;          // V*U bf16 = 25.6 MB
  if (ws_size < (size_t)kV * kU * sizeof(__hip_bfloat16)) return;

  ek_prepass<<<(kV + 127) / 128, 256, 0, stream>>>(emb, k0, b0, EK);
  rnn_persist<<<kB / 16, 512, 0, stream>>>(inputs, EK, rk0, k1, rk1, b1, wo, bo, out);
}